// Round 5
// baseline (263.506 us; speedup 1.0000x reference)
//
#include <hip/hip_runtime.h>
#include <math.h>

#define Bn 16
#define Cn 3
#define Hn 512
#define Wn 512
#define HWn (Hn*Wn)          // 262144
#define CHWn (Cn*HWn)        // 786432
#define Rr 4                 // rows per thread strip

__device__ __forceinline__ float clamp01(float x) {
    return fminf(fmaxf(x, 0.0f), 1.0f);
}

// ---------------------------------------------------------------------------
// Kernel 1: per-batch sum of gray(input_ir), gray = .2989 R + .587 G + .114 B
// grid = (32, B), block = 256. Each block sums 8192 pixels of one batch.
// Result accumulated in ws[b] (b = 0..15).
// ---------------------------------------------------------------------------
__global__ __launch_bounds__(256) void gray_mean_kernel(
        const float* __restrict__ ir, float* __restrict__ ws)
{
    const int b = blockIdx.y;
    const int tid = threadIdx.x;
    const float* base = ir + (size_t)b * CHWn;

    float sr = 0.f, sg = 0.f, sb = 0.f;
#pragma unroll
    for (int k = 0; k < 8; ++k) {
        size_t px = (size_t)blockIdx.x * 8192 + (size_t)(k * 256 + tid) * 4;
        float4 r4 = *(const float4*)(base + px);
        float4 g4 = *(const float4*)(base + HWn + px);
        float4 b4 = *(const float4*)(base + 2 * HWn + px);
        sr += (r4.x + r4.y) + (r4.z + r4.w);
        sg += (g4.x + g4.y) + (g4.z + g4.w);
        sb += (b4.x + b4.y) + (b4.z + b4.w);
    }
    float s = 0.2989f * sr + 0.587f * sg + 0.114f * sb;

#pragma unroll
    for (int off = 32; off; off >>= 1) s += __shfl_down(s, off, 64);

    __shared__ float red[4];
    if ((tid & 63) == 0) red[tid >> 6] = s;
    __syncthreads();
    if (tid == 0) atomicAdd(&ws[b], (red[0] + red[1]) + (red[2] + red[3]));
}

// ---------------------------------------------------------------------------
// Sobel pass over all 3 channels for one Rr-row strip.
// GUARDED=false (62/64 strips): the y-bounds check folds away and ALL loads
// (vec + clamped-address halo scalars) are UNCONDITIONAL -> the scheduler can
// hoist loads of later rows/channels above earlier compute and keep many
// loads in flight. Rounds 0/2/4 all pinned at ~97us / 2.1 TB/s / VALU 37%
// because every load sat behind a bounds branch: ~one 4KB row-tile in flight
// per wave ~= 2 TB/s chip-wide. This is the variable under test.
// Halo x-columns use clamped addresses + select (speculation-safe):
//   oL = ldl ? o_[o-1] : 0   with address o - ldl (always valid).
// OOB derived values are exactly 0 (fuse 0*0; rvis clamp01(sqrt(0));
// rir clamp01(-moff), moff>=0) == conv zero padding.
// ---------------------------------------------------------------------------
template<bool GUARDED>
__device__ __forceinline__ void sobel_channels(
        const float* __restrict__ pv, const float* __restrict__ pi,
        const float* __restrict__ po, const float* __restrict__ pm,
        int y0, int x0, float moff,
        float& conA, float& gxA, float& gyA)
{
    const int ldl = (x0 > 0) ? 1 : 0;
    const int ldr = (x0 + 4 < Wn) ? 1 : 0;
    const float fl = (float)ldl, fr = (float)ldr;

#define DECL_SLOT(S)                                                          \
    float wf##S##_0, wf##S##_1, wf##S##_2, wf##S##_3, wf##S##_4, wf##S##_5;   \
    float wv##S##_0, wv##S##_1, wv##S##_2, wv##S##_3, wv##S##_4, wv##S##_5;   \
    float wi##S##_0, wi##S##_1, wi##S##_2, wi##S##_3, wi##S##_4, wi##S##_5;

#define LOAD_ROW(Y, S)                                                        \
    do {                                                                      \
        const int y_ = (Y);                                                   \
        if (!GUARDED || (unsigned)y_ < (unsigned)Hn) {                        \
            const size_t o = (size_t)y_ * Wn + x0;                            \
            float4 o4 = *(const float4*)(o_ + o);                             \
            float4 m4 = *(const float4*)(m_ + o);                             \
            float4 v4 = *(const float4*)(v_ + o);                             \
            float4 i4 = *(const float4*)(i_ + o);                             \
            /* clamped-address halo loads: always in-bounds, zeroed by mul */ \
            float oL = fl * o_[o - ldl];     float oR = fr * o_[o + 3 + ldr]; \
            float mL = fl * m_[o - ldl];     float mR = fr * m_[o + 3 + ldr]; \
            float vL = fl * v_[o - ldl];     float vR = fr * v_[o + 3 + ldr]; \
            float iL = fl * i_[o - ldl];     float iR = fr * i_[o + 3 + ldr]; \
            wf##S##_0 = oL * mL;     wf##S##_1 = o4.x * m4.x;                 \
            wf##S##_2 = o4.y * m4.y; wf##S##_3 = o4.z * m4.z;                 \
            wf##S##_4 = o4.w * m4.w; wf##S##_5 = oR * mR;                     \
            wv##S##_0 = clamp01(sqrtf(vL));   wv##S##_1 = clamp01(sqrtf(v4.x)); \
            wv##S##_2 = clamp01(sqrtf(v4.y)); wv##S##_3 = clamp01(sqrtf(v4.z)); \
            wv##S##_4 = clamp01(sqrtf(v4.w)); wv##S##_5 = clamp01(sqrtf(vR));   \
            wi##S##_0 = fl * clamp01(fmaf(1.8f, iL,   -moff));                \
            wi##S##_1 = clamp01(fmaf(1.8f, i4.x, -moff));                     \
            wi##S##_2 = clamp01(fmaf(1.8f, i4.y, -moff));                     \
            wi##S##_3 = clamp01(fmaf(1.8f, i4.z, -moff));                     \
            wi##S##_4 = clamp01(fmaf(1.8f, i4.w, -moff));                     \
            wi##S##_5 = fr * clamp01(fmaf(1.8f, iR,   -moff));                \
        } else {                                                              \
            wf##S##_0=0.f; wf##S##_1=0.f; wf##S##_2=0.f;                      \
            wf##S##_3=0.f; wf##S##_4=0.f; wf##S##_5=0.f;                      \
            wv##S##_0=0.f; wv##S##_1=0.f; wv##S##_2=0.f;                      \
            wv##S##_3=0.f; wv##S##_4=0.f; wv##S##_5=0.f;                      \
            wi##S##_0=0.f; wi##S##_1=0.f; wi##S##_2=0.f;                      \
            wi##S##_3=0.f; wi##S##_4=0.f; wi##S##_5=0.f;                      \
        }                                                                     \
    } while (0)

// cross-correlation (XLA conv): no kernel flip. A = row y-1, B = y, C = y+1.
// gx = (A[x+1]-A[x-1]) + 2(B[x+1]-B[x-1]) + (C[x+1]-C[x-1])
// gy = (A[x-1]+2A[x]+A[x+1]) - (C[x-1]+2C[x]+C[x+1])
#define SOBEL_J(A, B, C, J0, J1, J2)                                          \
    do {                                                                      \
        float gxf = (wf##A##_##J2 - wf##A##_##J0) + 2.f * (wf##B##_##J2 - wf##B##_##J0) + (wf##C##_##J2 - wf##C##_##J0); \
        float gyf = (wf##A##_##J0 + 2.f * wf##A##_##J1 + wf##A##_##J2) - (wf##C##_##J0 + 2.f * wf##C##_##J1 + wf##C##_##J2); \
        float gxv = (wv##A##_##J2 - wv##A##_##J0) + 2.f * (wv##B##_##J2 - wv##B##_##J0) + (wv##C##_##J2 - wv##C##_##J0); \
        float gyv = (wv##A##_##J0 + 2.f * wv##A##_##J1 + wv##A##_##J2) - (wv##C##_##J0 + 2.f * wv##C##_##J1 + wv##C##_##J2); \
        float gxi = (wi##A##_##J2 - wi##A##_##J0) + 2.f * (wi##B##_##J2 - wi##B##_##J0) + (wi##C##_##J2 - wi##C##_##J0); \
        float gyi = (wi##A##_##J0 + 2.f * wi##A##_##J1 + wi##A##_##J2) - (wi##C##_##J0 + 2.f * wi##C##_##J1 + wi##C##_##J2); \
        gxA  += fabsf(gxf - fmaxf(gxv, gxi));                                 \
        gyA  += fabsf(gyf - fmaxf(gyv, gyi));                                 \
        conA += fabsf(wf##B##_##J1 - fmaxf(wv##B##_##J1, wi##B##_##J1));      \
    } while (0)

#define STEP(A, B, C)                                                         \
    SOBEL_J(A, B, C, 0, 1, 2); SOBEL_J(A, B, C, 1, 2, 3);                     \
    SOBEL_J(A, B, C, 2, 3, 4); SOBEL_J(A, B, C, 3, 4, 5)

#pragma unroll
    for (int c = 0; c < 3; ++c) {
        const float* v_ = pv + (size_t)c * HWn;
        const float* i_ = pi + (size_t)c * HWn;
        const float* o_ = po + (size_t)c * HWn;
        const float* m_ = pm + (size_t)c * HWn;

        DECL_SLOT(0) DECL_SLOT(1) DECL_SLOT(2)

        LOAD_ROW(y0 - 1, 0);                  // slot0 = row y0-1
        LOAD_ROW(y0,     1);                  // slot1 = row y0
        LOAD_ROW(y0 + 1, 2); STEP(0, 1, 2);   // out row y0
        LOAD_ROW(y0 + 2, 0); STEP(1, 2, 0);   // out row y0+1
        LOAD_ROW(y0 + 3, 1); STEP(2, 0, 1);   // out row y0+2
        LOAD_ROW(y0 + 4, 2); STEP(0, 1, 2);   // out row y0+3
    }
#undef STEP
#undef SOBEL_J
#undef LOAD_ROW
#undef DECL_SLOT
}

// ---------------------------------------------------------------------------
// Kernel 2: main fused kernel.
// grid = (Hn/(2*Rr), B) = (64,16) = 1024 blocks, block = 256.
// tx = tid&127 -> x0 = 4*tx (512 cols), sy = tid>>7 -> two Rr-row strips.
// Strips touching rows -1/512 (y0==0, y0==508) take the GUARDED path; that
// split is wave-uniform (sy = tid>>7). Everything else is branch-free.
// Accumulates into ws[16..20]: con, gx, gy, cr, cb sums.
// ---------------------------------------------------------------------------
__global__ __launch_bounds__(256) void fusion_main_kernel(
        const float* __restrict__ vis, const float* __restrict__ ir,
        const float* __restrict__ outp, const float* __restrict__ mask,
        float* __restrict__ ws)
{
    const int tid = threadIdx.x;
    const int tx = tid & 127;
    const int sy = tid >> 7;
    const int b  = blockIdx.y;
    const int y0 = (blockIdx.x * 2 + sy) * Rr;
    const int x0 = tx * 4;

    const float mean_b = ws[b] * (1.0f / (float)HWn);
    const float moff = 0.8f * mean_b;   // R_ir = clamp01(1.8*ir - moff), moff >= 0

    const size_t bb = (size_t)b * CHWn;
    const float* pv = vis  + bb;
    const float* pi = ir   + bb;
    const float* po = outp + bb;
    const float* pm = mask + bb;

    float conA = 0.f, gxA = 0.f, gyA = 0.f;

    if (y0 > 0 && y0 + Rr < Hn) {
        sobel_channels<false>(pv, pi, po, pm, y0, x0, moff, conA, gxA, gyA);
    } else {
        sobel_channels<true >(pv, pi, po, pm, y0, x0, moff, conA, gxA, gyA);
    }

    // ---------------- color pass (center pixels, all 3 channels) ----------------
    // Re-reads 9 planes of the strip just touched by the sobel pass -> LLC
    // hits, negligible extra HBM traffic (FETCH measured ~201MB vs 192MB min).
    float crA = 0.f, cbA = 0.f;
    {
        for (int y = y0; y < y0 + Rr; ++y) {
            size_t o = (size_t)y * Wn + x0;
            float4 oR = *(const float4*)(po + o);
            float4 oG = *(const float4*)(po + HWn + o);
            float4 oB = *(const float4*)(po + 2 * HWn + o);
            float4 mR = *(const float4*)(pm + o);
            float4 mG = *(const float4*)(pm + HWn + o);
            float4 mB = *(const float4*)(pm + 2 * HWn + o);
            float4 vR = *(const float4*)(pv + o);
            float4 vG = *(const float4*)(pv + HWn + o);
            float4 vB = *(const float4*)(pv + 2 * HWn + o);
#define COLOR_PX(FR, FG, FB, VR, VG, VB)                                      \
            do {                                                              \
                float fr = (FR), fg = (FG), fb = (FB);                        \
                float vr = (VR), vg = (VG), vb = (VB);                        \
                float fY = 0.299f * fr + 0.587f * fg + 0.114f * fb;           \
                float vY = 0.299f * vr + 0.587f * vg + 0.114f * vb;           \
                crA += fabsf((fr - fY) * 0.713f - (vr - vY) * 0.713f);        \
                cbA += fabsf((fb - fY) * 0.564f - (vb - vY) * 0.564f);        \
            } while (0)
            COLOR_PX(oR.x * mR.x, oG.x * mG.x, oB.x * mB.x,
                     clamp01(sqrtf(vR.x)), clamp01(sqrtf(vG.x)), clamp01(sqrtf(vB.x)));
            COLOR_PX(oR.y * mR.y, oG.y * mG.y, oB.y * mB.y,
                     clamp01(sqrtf(vR.y)), clamp01(sqrtf(vG.y)), clamp01(sqrtf(vB.y)));
            COLOR_PX(oR.z * mR.z, oG.z * mG.z, oB.z * mB.z,
                     clamp01(sqrtf(vR.z)), clamp01(sqrtf(vG.z)), clamp01(sqrtf(vB.z)));
            COLOR_PX(oR.w * mR.w, oG.w * mG.w, oB.w * mB.w,
                     clamp01(sqrtf(vR.w)), clamp01(sqrtf(vG.w)), clamp01(sqrtf(vB.w)));
#undef COLOR_PX
        }
    }

    // ---------------- block reduction + atomics ----------------
    auto wred = [](float x) {
#pragma unroll
        for (int off = 32; off; off >>= 1) x += __shfl_down(x, off, 64);
        return x;
    };
    conA = wred(conA); gxA = wred(gxA); gyA = wred(gyA);
    crA  = wred(crA);  cbA = wred(cbA);

    __shared__ float red[5][4];
    const int lane = tid & 63, w = tid >> 6;
    if (lane == 0) {
        red[0][w] = conA; red[1][w] = gxA; red[2][w] = gyA;
        red[3][w] = crA;  red[4][w] = cbA;
    }
    __syncthreads();
    if (tid < 5) {
        float s = (red[tid][0] + red[tid][1]) + (red[tid][2] + red[tid][3]);
        atomicAdd(&ws[16 + tid], s);
    }
}

// ---------------------------------------------------------------------------
// Kernel 3: finalize scalar loss.
// loss = 0.5*con + 0.2*(0.5*gx + 0.5*gy) + (cb + cr)
// con/gx/gy means over B*3*H*W; cr/cb means over B*1*H*W.
// ---------------------------------------------------------------------------
__global__ void finalize_kernel(const float* __restrict__ ws, float* __restrict__ out)
{
    if (threadIdx.x == 0 && blockIdx.x == 0) {
        const float invN3 = 1.0f / (float)((size_t)Bn * Cn * HWn);
        const float invN1 = 1.0f / (float)((size_t)Bn * HWn);
        float con = ws[16] * invN3;
        float gx  = ws[17] * invN3;
        float gy  = ws[18] * invN3;
        float cr  = ws[19] * invN1;
        float cb  = ws[20] * invN1;
        out[0] = 0.5f * con + 0.2f * (0.5f * gx + 0.5f * gy) + (cb + cr);
    }
}

extern "C" void kernel_launch(void* const* d_in, const int* in_sizes, int n_in,
                              void* d_out, int out_size, void* d_ws, size_t ws_size,
                              hipStream_t stream)
{
    const float* vis = (const float*)d_in[0];
    const float* ir  = (const float*)d_in[1];
    const float* out = (const float*)d_in[2];
    const float* msk = (const float*)d_in[3];
    float* ws = (float*)d_ws;

    // ws[0..15] = per-batch gray sums; ws[16..20] = loss accumulators
    hipMemsetAsync(ws, 0, 32 * sizeof(float), stream);

    gray_mean_kernel<<<dim3(32, Bn), 256, 0, stream>>>(ir, ws);
    fusion_main_kernel<<<dim3(Hn / (2 * Rr), Bn), 256, 0, stream>>>(vis, ir, out, msk, ws);
    finalize_kernel<<<1, 64, 0, stream>>>(ws, (float*)d_out);
}

// Round 7
// 240.145 us; speedup vs baseline: 1.0973x; 1.0973x over previous
//
#include <hip/hip_runtime.h>
#include <math.h>

#define Bn 16
#define Cn 3
#define Hn 512
#define Wn 512
#define HWn (Hn*Wn)          // 262144
#define CHWn (Cn*HWn)        // 786432
#define Rr 4                 // output rows per block

__device__ __forceinline__ float clamp01(float x) {
    return fminf(fmaxf(x, 0.0f), 1.0f);
}

// async global->LDS, 16B per lane, dest = wave-uniform base + lane*16 (m97/m104)
__device__ __forceinline__ void gload_lds16(const float* g, float* l) {
    __builtin_amdgcn_global_load_lds(
        (const __attribute__((address_space(1))) void*)g,
        (__attribute__((address_space(3))) void*)l, 16, 0, 0);
}

// ---------------------------------------------------------------------------
// Kernel 1: per-batch sum of gray(input_ir), gray = .2989 R + .587 G + .114 B
// ---------------------------------------------------------------------------
__global__ __launch_bounds__(256) void gray_mean_kernel(
        const float* __restrict__ ir, float* __restrict__ ws)
{
    const int b = blockIdx.y;
    const int tid = threadIdx.x;
    const float* base = ir + (size_t)b * CHWn;

    float sr = 0.f, sg = 0.f, sb = 0.f;
#pragma unroll
    for (int k = 0; k < 8; ++k) {
        size_t px = (size_t)blockIdx.x * 8192 + (size_t)(k * 256 + tid) * 4;
        float4 r4 = *(const float4*)(base + px);
        float4 g4 = *(const float4*)(base + HWn + px);
        float4 b4 = *(const float4*)(base + 2 * HWn + px);
        sr += (r4.x + r4.y) + (r4.z + r4.w);
        sg += (g4.x + g4.y) + (g4.z + g4.w);
        sb += (b4.x + b4.y) + (b4.z + b4.w);
    }
    float s = 0.2989f * sr + 0.587f * sg + 0.114f * sb;

#pragma unroll
    for (int off = 32; off; off >>= 1) s += __shfl_down(s, off, 64);

    __shared__ float red[4];
    if ((tid & 63) == 0) red[tid >> 6] = s;
    __syncthreads();
    if (tid == 0) atomicAdd(&ws[b], (red[0] + red[1]) + (red[2] + red[3]));
}

// ---------------------------------------------------------------------------
// Kernel 2: LDS-staged fused kernel.
// Per channel: each of the 4 waves async-stages ONE tensor's 6 rows (12 KB
// sequential, 12 x global_load_lds_dwordx4, no VGPR round-trip) -> barrier ->
// compute sobel+con+color from LDS -> barrier. Color loss is merged into the
// channel loop via cross-channel register accumulators (fY/vY running dots,
// R-channel capture) -- the old separate color pass is gone.
// Layout: tx = tid&127 -> x0 = 4*tx; sy = tid>>7 -> 2 output rows each
// (block outputs rows y0..y0+3). Windows = named scalars (R4). Halo columns
// read as clamped-address float4 from LDS (conflict-free), zeroed by fl/fr.
// LDS 48 KB -> 3 blocks/CU. grid (128,16) = 2048 blocks.
// ---------------------------------------------------------------------------

#define DECL_SLOT(S)                                                          \
    float wf##S##_0, wf##S##_1, wf##S##_2, wf##S##_3, wf##S##_4, wf##S##_5;   \
    float wv##S##_0, wv##S##_1, wv##S##_2, wv##S##_3, wv##S##_4, wv##S##_5;   \
    float wi##S##_0, wi##S##_1, wi##S##_2, wi##S##_3, wi##S##_4, wi##S##_5;

#define DECL_COL(RO)                                                          \
    float cfY_##RO##_1=0.f, cfY_##RO##_2=0.f, cfY_##RO##_3=0.f, cfY_##RO##_4=0.f; \
    float cvY_##RO##_1=0.f, cvY_##RO##_2=0.f, cvY_##RO##_3=0.f, cvY_##RO##_4=0.f; \
    float cfr_##RO##_1=0.f, cfr_##RO##_2=0.f, cfr_##RO##_3=0.f, cfr_##RO##_4=0.f; \
    float cvr_##RO##_1=0.f, cvr_##RO##_2=0.f, cvr_##RO##_3=0.f, cvr_##RO##_4=0.f;

// Build window slot S from LDS row (sy2+LL). OOB rows (guarded blocks only)
// become exact zeros == conv zero-padding (fuse 0*0; rvis clamp01(sqrt(0));
// rir clamp01(-moff), moff>=0). Halo cols via clamped-quad reads + fl/fr mul.
#define LOAD_ROW_LDS(LL, S)                                                   \
    do {                                                                      \
        const int rr_ = sy2 + (LL);                                           \
        if (!GUARDED || (unsigned)(y0 - 1 + rr_) < (unsigned)Hn) {            \
            const float4 o4 = *(const float4*)&lds[0][rr_][x0];               \
            const float4 m4 = *(const float4*)&lds[1][rr_][x0];               \
            const float4 v4 = *(const float4*)&lds[2][rr_][x0];               \
            const float4 i4 = *(const float4*)&lds[3][rr_][x0];               \
            const float4 oq = *(const float4*)&lds[0][rr_][x0 - 4*ldl];       \
            const float4 mq = *(const float4*)&lds[1][rr_][x0 - 4*ldl];       \
            const float4 vq = *(const float4*)&lds[2][rr_][x0 - 4*ldl];       \
            const float4 iq = *(const float4*)&lds[3][rr_][x0 - 4*ldl];       \
            const float4 oz = *(const float4*)&lds[0][rr_][x0 + 4*ldr];       \
            const float4 mz = *(const float4*)&lds[1][rr_][x0 + 4*ldr];       \
            const float4 vz = *(const float4*)&lds[2][rr_][x0 + 4*ldr];       \
            const float4 iz = *(const float4*)&lds[3][rr_][x0 + 4*ldr];       \
            const float oL = fl * oq.w, oR = fr * oz.x;                       \
            const float mL = fl * mq.w, mR = fr * mz.x;                       \
            const float vL = fl * vq.w, vR = fr * vz.x;                       \
            const float iL = fl * iq.w, iR = fr * iz.x;                       \
            wf##S##_0 = oL * mL;     wf##S##_1 = o4.x * m4.x;                 \
            wf##S##_2 = o4.y * m4.y; wf##S##_3 = o4.z * m4.z;                 \
            wf##S##_4 = o4.w * m4.w; wf##S##_5 = oR * mR;                     \
            wv##S##_0 = clamp01(sqrtf(vL));   wv##S##_1 = clamp01(sqrtf(v4.x)); \
            wv##S##_2 = clamp01(sqrtf(v4.y)); wv##S##_3 = clamp01(sqrtf(v4.z)); \
            wv##S##_4 = clamp01(sqrtf(v4.w)); wv##S##_5 = clamp01(sqrtf(vR));   \
            wi##S##_0 = fl * clamp01(fmaf(1.8f, iL,   -moff));                \
            wi##S##_1 = clamp01(fmaf(1.8f, i4.x, -moff));                     \
            wi##S##_2 = clamp01(fmaf(1.8f, i4.y, -moff));                     \
            wi##S##_3 = clamp01(fmaf(1.8f, i4.z, -moff));                     \
            wi##S##_4 = clamp01(fmaf(1.8f, i4.w, -moff));                     \
            wi##S##_5 = fr * clamp01(fmaf(1.8f, iR,   -moff));                \
        } else {                                                              \
            wf##S##_0=0.f; wf##S##_1=0.f; wf##S##_2=0.f;                      \
            wf##S##_3=0.f; wf##S##_4=0.f; wf##S##_5=0.f;                      \
            wv##S##_0=0.f; wv##S##_1=0.f; wv##S##_2=0.f;                      \
            wv##S##_3=0.f; wv##S##_4=0.f; wv##S##_5=0.f;                      \
            wi##S##_0=0.f; wi##S##_1=0.f; wi##S##_2=0.f;                      \
            wi##S##_3=0.f; wi##S##_4=0.f; wi##S##_5=0.f;                      \
        }                                                                     \
    } while (0)

// cross-correlation (XLA conv): no kernel flip. A = row y-1, B = y, C = y+1.
// Also: con-loss at center, Y-dot accumulation + R-capture for color loss.
#define SOBEL_J(A, B, C, J0, J1, J2, RO)                                      \
    do {                                                                      \
        float gxf = (wf##A##_##J2 - wf##A##_##J0) + 2.f * (wf##B##_##J2 - wf##B##_##J0) + (wf##C##_##J2 - wf##C##_##J0); \
        float gyf = (wf##A##_##J0 + 2.f * wf##A##_##J1 + wf##A##_##J2) - (wf##C##_##J0 + 2.f * wf##C##_##J1 + wf##C##_##J2); \
        float gxv = (wv##A##_##J2 - wv##A##_##J0) + 2.f * (wv##B##_##J2 - wv##B##_##J0) + (wv##C##_##J2 - wv##C##_##J0); \
        float gyv = (wv##A##_##J0 + 2.f * wv##A##_##J1 + wv##A##_##J2) - (wv##C##_##J0 + 2.f * wv##C##_##J1 + wv##C##_##J2); \
        float gxi = (wi##A##_##J2 - wi##A##_##J0) + 2.f * (wi##B##_##J2 - wi##B##_##J0) + (wi##C##_##J2 - wi##C##_##J0); \
        float gyi = (wi##A##_##J0 + 2.f * wi##A##_##J1 + wi##A##_##J2) - (wi##C##_##J0 + 2.f * wi##C##_##J1 + wi##C##_##J2); \
        gxA  += fabsf(gxf - fmaxf(gxv, gxi));                                 \
        gyA  += fabsf(gyf - fmaxf(gyv, gyi));                                 \
        float f1 = wf##B##_##J1, v1 = wv##B##_##J1;                           \
        conA += fabsf(f1 - fmaxf(v1, wi##B##_##J1));                          \
        cfY_##RO##_##J1 = fmaf(coefc, f1, cfY_##RO##_##J1);                   \
        cvY_##RO##_##J1 = fmaf(coefc, v1, cvY_##RO##_##J1);                   \
        if (c == 0) { cfr_##RO##_##J1 = f1; cvr_##RO##_##J1 = v1; }           \
        if (c == 2) {                                                         \
            crA += fabsf(0.713f * ((cfr_##RO##_##J1 - cfY_##RO##_##J1)        \
                                 - (cvr_##RO##_##J1 - cvY_##RO##_##J1)));     \
            cbA += fabsf(0.564f * ((f1 - cfY_##RO##_##J1)                     \
                                 - (v1 - cvY_##RO##_##J1)));                  \
        }                                                                     \
    } while (0)

#define STEP(A, B, C, RO)                                                     \
    SOBEL_J(A, B, C, 0, 1, 2, RO); SOBEL_J(A, B, C, 1, 2, 3, RO);             \
    SOBEL_J(A, B, C, 2, 3, 4, RO); SOBEL_J(A, B, C, 3, 4, 5, RO)

template<bool GUARDED>
__device__ __forceinline__ void fusion_body(
        const float* __restrict__ pv, const float* __restrict__ pi,
        const float* __restrict__ po, const float* __restrict__ pm,
        int y0, int tid, float moff,
        float& conA, float& gxA, float& gyA, float& crA, float& cbA,
        float (&lds)[4][6][512])
{
    const int tx = tid & 127;
    const int sy = tid >> 7;           // 0/1: which pair of output rows
    const int sy2 = sy * 2;
    const int x0 = tx * 4;
    const int ldl = (x0 > 0) ? 1 : 0;
    const int ldr = (x0 + 4 < Wn) ? 1 : 0;
    const float fl = (float)ldl, fr = (float)ldr;
    const int wv = tid >> 6;           // wave id 0..3 -> staged tensor
    const int lane = tid & 63;
    const float* tb = (wv == 0) ? po : (wv == 1) ? pm : (wv == 2) ? pv : pi;

    DECL_COL(0) DECL_COL(1)

#pragma unroll 1
    for (int c = 0; c < 3; ++c) {
        const float coefc = (c == 0) ? 0.299f : (c == 1) ? 0.587f : 0.114f;
        const float* tc = tb + (size_t)c * HWn;

        // ---- async stage: wave wv stages tensor wv, rows y0-1..y0+4,
        //      12 KB sequential as 12 back-to-back 1-KB global_load_lds.
#pragma unroll
        for (int k = 0; k < 12; ++k) {
            const int r = k >> 1, h = k & 1;
            int ys = y0 - 1 + r;
            if (GUARDED) ys = ys < 0 ? 0 : (ys >= Hn ? Hn - 1 : ys);  // staged but never read
            gload_lds16(tc + (size_t)ys * Wn + h * 256 + lane * 4,
                        &lds[wv][r][h * 256]);
        }
        __syncthreads();   // compiler drains vmcnt(0) before barrier (m97)

        DECL_SLOT(0) DECL_SLOT(1) DECL_SLOT(2)
        LOAD_ROW_LDS(0, 0);
        LOAD_ROW_LDS(1, 1);
        LOAD_ROW_LDS(2, 2); STEP(0, 1, 2, 0);   // out row y0 + sy2
        LOAD_ROW_LDS(3, 0); STEP(1, 2, 0, 1);   // out row y0 + sy2 + 1
        __syncthreads();   // before next channel's stage overwrites lds
    }
}

__global__ __launch_bounds__(256, 3) void fusion_main_kernel(
        const float* __restrict__ vis, const float* __restrict__ ir,
        const float* __restrict__ outp, const float* __restrict__ mask,
        float* __restrict__ ws)
{
    __shared__ float lds[4][6][512];   // 48 KB: [tensor][row][col]
    const int tid = threadIdx.x;
    const int b   = blockIdx.y;
    const int y0  = blockIdx.x * Rr;

    const float mean_b = ws[b] * (1.0f / (float)HWn);
    const float moff = 0.8f * mean_b;  // R_ir = clamp01(1.8*ir - moff), moff >= 0

    const size_t bb = (size_t)b * CHWn;
    const float* pv = vis  + bb;
    const float* pi = ir   + bb;
    const float* po = outp + bb;
    const float* pm = mask + bb;

    float conA = 0.f, gxA = 0.f, gyA = 0.f, crA = 0.f, cbA = 0.f;

    if (blockIdx.x == 0 || blockIdx.x == gridDim.x - 1)
        fusion_body<true >(pv, pi, po, pm, y0, tid, moff, conA, gxA, gyA, crA, cbA, lds);
    else
        fusion_body<false>(pv, pi, po, pm, y0, tid, moff, conA, gxA, gyA, crA, cbA, lds);

    // ---------------- block reduction + atomics (reuse lds) ----------------
    auto wred = [](float x) {
#pragma unroll
        for (int off = 32; off; off >>= 1) x += __shfl_down(x, off, 64);
        return x;
    };
    conA = wred(conA); gxA = wred(gxA); gyA = wred(gyA);
    crA  = wred(crA);  cbA = wred(cbA);

    float* red = &lds[0][0][0];        // safe: body ends with __syncthreads()
    const int lane = tid & 63, w = tid >> 6;
    if (lane == 0) {
        red[0 * 4 + w] = conA; red[1 * 4 + w] = gxA; red[2 * 4 + w] = gyA;
        red[3 * 4 + w] = crA;  red[4 * 4 + w] = cbA;
    }
    __syncthreads();
    if (tid < 5) {
        float s = (red[tid * 4 + 0] + red[tid * 4 + 1])
                + (red[tid * 4 + 2] + red[tid * 4 + 3]);
        atomicAdd(&ws[16 + tid], s);
    }
}

#undef STEP
#undef SOBEL_J
#undef LOAD_ROW_LDS
#undef DECL_COL
#undef DECL_SLOT

// ---------------------------------------------------------------------------
// Kernel 3: finalize scalar loss.
// loss = 0.5*con + 0.2*(0.5*gx + 0.5*gy) + (cb + cr)
// ---------------------------------------------------------------------------
__global__ void finalize_kernel(const float* __restrict__ ws, float* __restrict__ out)
{
    if (threadIdx.x == 0 && blockIdx.x == 0) {
        const float invN3 = 1.0f / (float)((size_t)Bn * Cn * HWn);
        const float invN1 = 1.0f / (float)((size_t)Bn * HWn);
        float con = ws[16] * invN3;
        float gx  = ws[17] * invN3;
        float gy  = ws[18] * invN3;
        float cr  = ws[19] * invN1;
        float cb  = ws[20] * invN1;
        out[0] = 0.5f * con + 0.2f * (0.5f * gx + 0.5f * gy) + (cb + cr);
    }
}

extern "C" void kernel_launch(void* const* d_in, const int* in_sizes, int n_in,
                              void* d_out, int out_size, void* d_ws, size_t ws_size,
                              hipStream_t stream)
{
    const float* vis = (const float*)d_in[0];
    const float* ir  = (const float*)d_in[1];
    const float* out = (const float*)d_in[2];
    const float* msk = (const float*)d_in[3];
    float* ws = (float*)d_ws;

    // ws[0..15] = per-batch gray sums; ws[16..20] = loss accumulators
    hipMemsetAsync(ws, 0, 32 * sizeof(float), stream);

    gray_mean_kernel<<<dim3(32, Bn), 256, 0, stream>>>(ir, ws);
    fusion_main_kernel<<<dim3(Hn / Rr, Bn), 256, 0, stream>>>(vis, ir, out, msk, ws);
    finalize_kernel<<<1, 64, 0, stream>>>(ws, (float*)d_out);
}